// Round 2
// baseline (1581.215 us; speedup 1.0000x reference)
//
#include <hip/hip_runtime.h>
#include <hip/hip_bf16.h>
#include <cstdint>
#include <cstddef>

// Problem constants (NeuTraLAD): B=8192, D=512, H=1024, K=11 views.
#define NB 8192
#define ND 512
#define NH 1024
#define NK 11

typedef __bf16 bf16x8 __attribute__((ext_vector_type(8)));
typedef float f32x4 __attribute__((ext_vector_type(4)));

// ---------------------------------------------------------------------------
// Convert f32 -> bf16 elementwise
// ---------------------------------------------------------------------------
__global__ void cvt_f32_bf16(const float* __restrict__ in,
                             __hip_bfloat16* __restrict__ out, int n) {
  int i = blockIdx.x * blockDim.x + threadIdx.x;
  if (i < n) out[i] = __float2bfloat16(in[i]);
}

// ---------------------------------------------------------------------------
// Transpose f32 [R,C] -> bf16 [C,R], batched over blockIdx.z (stride R*C)
// ---------------------------------------------------------------------------
__global__ void transpose_f32_bf16(const float* __restrict__ in,
                                   __hip_bfloat16* __restrict__ out,
                                   int R, int C) {
  __shared__ float tile[32][33];
  const float* inb = in + (size_t)blockIdx.z * R * C;
  __hip_bfloat16* outb = out + (size_t)blockIdx.z * R * C;
  int cx = blockIdx.x * 32 + threadIdx.x;  // input col
  int ry = blockIdx.y * 32;                // input row base
  for (int j = threadIdx.y; j < 32; j += 8)
    tile[j][threadIdx.x] = inb[(size_t)(ry + j) * C + cx];
  __syncthreads();
  int ox = ry + threadIdx.x;  // output col = input row
  int oy = blockIdx.x * 32;   // output row base = input col base
  for (int j = threadIdx.y; j < 32; j += 8)
    outb[(size_t)(oy + j) * R + ox] = __float2bfloat16(tile[threadIdx.x][j]);
}

// ---------------------------------------------------------------------------
// MFMA GEMM (NT): C[M,N] = act(A[M,Kd] * Bt[N,Kd]^T + bias[N])
// 128x128 block tile, BK=32, 256 threads = 4 waves (2x2), each wave 4x4
// tiles of mfma_f32_16x16x32_bf16. global_load_lds width-16 staging.
// Batched over blockIdx.z with element strides sAz/sBz/sBiasZ/sCz.
// EPI: 1 = tanh->bf16, 2 = relu->bf16, 3 = plain->bf16
// M,N,Kd must be multiples of 128/128/32 (true for all shapes here).
// ---------------------------------------------------------------------------
template <int EPI>
__global__ __launch_bounds__(256) void gemm_bt(
    const __hip_bfloat16* __restrict__ A, long sAz, int lda,
    const __hip_bfloat16* __restrict__ Bt, long sBz, int ldb,
    const float* __restrict__ bias, long sBiasZ,
    __hip_bfloat16* __restrict__ C, long sCz, int ldc, int Kd) {
  __shared__ __align__(16) __hip_bfloat16 As[128 * 32];
  __shared__ __align__(16) __hip_bfloat16 Bs[128 * 32];

  const int z = blockIdx.z;
  const __hip_bfloat16* Ab = A + (size_t)z * sAz;
  const __hip_bfloat16* Bb = Bt + (size_t)z * sBz;
  const float* biasb = bias + (size_t)z * sBiasZ;
  __hip_bfloat16* Cb = C + (size_t)z * sCz;

  const int bm = blockIdx.y, bn = blockIdx.x;
  const int t = threadIdx.x;
  const int lane = t & 63, w = t >> 6;
  const int wm = w >> 1, wn = w & 1;
  const int r = lane & 15, q = lane >> 4;

  f32x4 acc[4][4] = {};

  // staging: 512 chunks of 16B per tile; thread handles chunks t and t+256
  const int c0 = t, c1 = t + 256;
  const int rA0 = c0 >> 2, cc0 = (c0 & 3) * 8;
  const int rA1 = c1 >> 2, cc1 = (c1 & 3) * 8;
  const size_t rowA = (size_t)bm * 128, rowB = (size_t)bn * 128;

  for (int k0 = 0; k0 < Kd; k0 += 32) {
    __builtin_amdgcn_global_load_lds(
        (const __attribute__((address_space(1))) void*)(Ab + (rowA + rA0) * lda + k0 + cc0),
        (__attribute__((address_space(3))) void*)(As + c0 * 8), 16, 0, 0);
    __builtin_amdgcn_global_load_lds(
        (const __attribute__((address_space(1))) void*)(Ab + (rowA + rA1) * lda + k0 + cc1),
        (__attribute__((address_space(3))) void*)(As + c1 * 8), 16, 0, 0);
    __builtin_amdgcn_global_load_lds(
        (const __attribute__((address_space(1))) void*)(Bb + (rowB + rA0) * ldb + k0 + cc0),
        (__attribute__((address_space(3))) void*)(Bs + c0 * 8), 16, 0, 0);
    __builtin_amdgcn_global_load_lds(
        (const __attribute__((address_space(1))) void*)(Bb + (rowB + rA1) * ldb + k0 + cc1),
        (__attribute__((address_space(3))) void*)(Bs + c1 * 8), 16, 0, 0);
    __syncthreads();

    bf16x8 af[4], bfr[4];
#pragma unroll
    for (int mt = 0; mt < 4; ++mt)
      af[mt] = *(const bf16x8*)&As[(wm * 64 + mt * 16 + r) * 32 + q * 8];
#pragma unroll
    for (int nt = 0; nt < 4; ++nt)
      bfr[nt] = *(const bf16x8*)&Bs[(wn * 64 + nt * 16 + r) * 32 + q * 8];
#pragma unroll
    for (int mt = 0; mt < 4; ++mt)
#pragma unroll
      for (int nt = 0; nt < 4; ++nt)
        acc[mt][nt] = __builtin_amdgcn_mfma_f32_16x16x32_bf16(
            af[mt], bfr[nt], acc[mt][nt], 0, 0, 0);
    __syncthreads();
  }

  // Epilogue: C/D layout col = lane&15, row = q*4 + j  [m89-verified]
  const int colg0 = bn * 128 + wn * 64;
  const int rowg0 = bm * 128 + wm * 64;
#pragma unroll
  for (int nt = 0; nt < 4; ++nt) {
    int col = colg0 + nt * 16 + r;
    float bv = biasb[col];
#pragma unroll
    for (int mt = 0; mt < 4; ++mt) {
      int row0 = rowg0 + mt * 16 + q * 4;
#pragma unroll
      for (int j = 0; j < 4; ++j) {
        float v = acc[mt][nt][j] + bv;
        if (EPI == 1) v = tanhf(v);
        if (EPI == 2) v = fmaxf(v, 0.0f);
        Cb[(size_t)(row0 + j) * ldc + col] = __float2bfloat16(v);
      }
    }
  }
}

// ---------------------------------------------------------------------------
// Final: per batch row b (within chunk of Bc rows), 12 encoded vectors
// (slice 0 = z from x, slices 1..11 = z_k). Gram -> normalize -> score.
// ---------------------------------------------------------------------------
__global__ __launch_bounds__(256) void final_reduce(
    const __hip_bfloat16* __restrict__ zall, float* __restrict__ out, int Bc) {
  __shared__ float V[12][NH];
  __shared__ float G[12][12];
  const int b = blockIdx.x;
  const int t = threadIdx.x;
  for (int s = 0; s < 12; ++s)
    for (int h = t; h < NH; h += 256)
      V[s][h] = __bfloat162float(zall[((size_t)s * Bc + b) * NH + h]);
  __syncthreads();

  const int lane = t & 63, w = t >> 6;
  int p = 0;
  for (int i = 0; i < 12; ++i) {
    for (int j = i; j < 12; ++j) {
      if ((p & 3) == w) {
        float s = 0.0f;
        for (int h = lane; h < NH; h += 64) s += V[i][h] * V[j][h];
#pragma unroll
        for (int m = 32; m; m >>= 1) s += __shfl_xor(s, m);
        if (lane == 0) {
          G[i][j] = s;
          G[j][i] = s;
        }
      }
      ++p;
    }
  }
  __syncthreads();

  if (t == 0) {
    float nrm[12];
    for (int i = 0; i < 12; ++i) nrm[i] = fmaxf(sqrtf(G[i][i]), 1e-8f);
    float acc = 0.0f;
    for (int k = 1; k < 12; ++k) {
      float pos = expf(G[0][k] / (nrm[0] * nrm[k]));
      float neg = 0.0f;
      for (int l = 1; l < 12; ++l)
        if (l != k) neg += expf(G[k][l] / (nrm[k] * nrm[l]));
      acc += logf(pos / (pos + neg));
    }
    out[b] = -acc;
  }
}

// ---------------------------------------------------------------------------
extern "C" void kernel_launch(void* const* d_in, const int* in_sizes, int n_in,
                              void* d_out, int out_size, void* d_ws,
                              size_t ws_size, hipStream_t stream) {
  const float* x = (const float*)d_in[0];    // [B,D]
  const float* Wt1 = (const float*)d_in[1];  // [K,D,H]
  const float* bt1 = (const float*)d_in[2];  // [K,H]
  const float* Wt2 = (const float*)d_in[3];  // [K,H,D]
  const float* bt2 = (const float*)d_in[4];  // [K,D]
  const float* We1 = (const float*)d_in[5];  // [D,H]
  const float* be1 = (const float*)d_in[6];  // [H]
  const float* We2 = (const float*)d_in[7];  // [H,H]
  const float* be2 = (const float*)d_in[8];  // [H]
  float* out = (float*)d_out;                // [B]

  char* ws = (char*)d_ws;
  size_t off = 0;
  auto alloc = [&](size_t bytes) {
    void* p = ws + off;
    off += (bytes + 255) & ~(size_t)255;
    return p;
  };

  // Persistent bf16 weight transposes (~26 MB)
  __hip_bfloat16* Wt1t = (__hip_bfloat16*)alloc((size_t)NK * NH * ND * 2);  // [K,H,D]
  __hip_bfloat16* Wt2t = (__hip_bfloat16*)alloc((size_t)NK * ND * NH * 2);  // [K,D,H]
  __hip_bfloat16* We1t = (__hip_bfloat16*)alloc((size_t)NH * ND * 2);       // [H,D]
  __hip_bfloat16* We2t = (__hip_bfloat16*)alloc((size_t)NH * NH * 2);       // [H,H]
  const size_t wbytes = off;

  // Pick largest batch chunk Bc whose buffers fit in ws_size:
  // need = wbytes + 12*Bc*D*2 (tx) + 2 * 12*Bc*H*2 (h1, z) + slack
  int Bc = NB;
  while (Bc > 128) {
    size_t need = wbytes + (size_t)12 * Bc * ND * 2 +
                  2 * ((size_t)12 * Bc * NH * 2) + 4096;
    if (need <= ws_size) break;
    Bc >>= 1;
  }
  // Per-chunk buffers:
  // txc: 12 slices [Bc,D] bf16; slice 0 = x(bf16), 1..11 = tx_k
  __hip_bfloat16* txc = (__hip_bfloat16*)alloc((size_t)12 * Bc * ND * 2);
  // h1: [12,Bc,H] bf16; holds hx (slices 0..10), then e1 (slices 0..11)
  __hip_bfloat16* h1 = (__hip_bfloat16*)alloc((size_t)12 * Bc * NH * 2);
  // zc: [12,Bc,H] bf16 encoded outputs
  __hip_bfloat16* zc = (__hip_bfloat16*)alloc((size_t)12 * Bc * NH * 2);

  // One-time weight transposes to bf16 [N][K] layout
  transpose_f32_bf16<<<dim3(NH / 32, ND / 32, NK), dim3(32, 8), 0, stream>>>(
      Wt1, Wt1t, ND, NH);
  transpose_f32_bf16<<<dim3(ND / 32, NH / 32, NK), dim3(32, 8), 0, stream>>>(
      Wt2, Wt2t, NH, ND);
  transpose_f32_bf16<<<dim3(NH / 32, ND / 32, 1), dim3(32, 8), 0, stream>>>(
      We1, We1t, ND, NH);
  transpose_f32_bf16<<<dim3(NH / 32, NH / 32, 1), dim3(32, 8), 0, stream>>>(
      We2, We2t, NH, NH);

  for (int cs = 0; cs < NB; cs += Bc) {
    // 1) x chunk -> bf16 (slice 0 of txc)
    cvt_f32_bf16<<<(Bc * ND) / 256, 256, 0, stream>>>(
        x + (size_t)cs * ND, txc, Bc * ND);
    // 2) G1: hx_k = tanh(x @ Wt1[k] + bt1) -> h1 slices 0..10  (M=Bc,N=H,Kd=D)
    gemm_bt<1><<<dim3(NH / 128, Bc / 128, NK), 256, 0, stream>>>(
        txc, 0L, ND, Wt1t, (long)NH * ND, ND, bt1, (long)NH, h1,
        (long)Bc * NH, NH, ND);
    // 3) G2: tx_k = hx_k @ Wt2[k] + bt2 -> txc slices 1..11    (M=Bc,N=D,Kd=H)
    gemm_bt<3><<<dim3(ND / 128, Bc / 128, NK), 256, 0, stream>>>(
        h1, (long)Bc * NH, NH, Wt2t, (long)ND * NH, NH, bt2, (long)ND,
        txc + (size_t)Bc * ND, (long)Bc * ND, ND, NH);
    // 4) G3: e1_s = relu(tx_s @ We1 + be1) -> h1 slices 0..11  (M=Bc,N=H,Kd=D)
    gemm_bt<2><<<dim3(NH / 128, Bc / 128, 12), 256, 0, stream>>>(
        txc, (long)Bc * ND, ND, We1t, 0L, ND, be1, 0L, h1, (long)Bc * NH,
        NH, ND);
    // 5) G4: z_s = e1_s @ We2 + be2 -> zc slices 0..11         (M=Bc,N=H,Kd=H)
    gemm_bt<3><<<dim3(NH / 128, Bc / 128, 12), 256, 0, stream>>>(
        h1, (long)Bc * NH, NH, We2t, 0L, NH, be2, 0L, zc, (long)Bc * NH,
        NH, NH);
    // 6) final score for this chunk
    final_reduce<<<Bc, 256, 0, stream>>>(zc, out + cs, Bc);
  }
}

// Round 3
// 1067.095 us; speedup vs baseline: 1.4818x; 1.4818x over previous
//
#include <hip/hip_runtime.h>
#include <hip/hip_bf16.h>
#include <cstdint>
#include <cstddef>

// Problem constants (NeuTraLAD): B=8192, D=512, H=1024, K=11 views.
#define NB 8192
#define ND 512
#define NH 1024
#define NK 11

typedef __bf16 bf16x8 __attribute__((ext_vector_type(8)));
typedef float f32x4 __attribute__((ext_vector_type(4)));

// ---------------------------------------------------------------------------
// Convert f32 -> bf16 elementwise
// ---------------------------------------------------------------------------
__global__ void cvt_f32_bf16(const float* __restrict__ in,
                             __hip_bfloat16* __restrict__ out, int n) {
  int i = blockIdx.x * blockDim.x + threadIdx.x;
  if (i < n) out[i] = __float2bfloat16(in[i]);
}

// ---------------------------------------------------------------------------
// Transpose f32 [R,C] -> bf16 [C,R], batched over blockIdx.z (stride R*C)
// ---------------------------------------------------------------------------
__global__ void transpose_f32_bf16(const float* __restrict__ in,
                                   __hip_bfloat16* __restrict__ out,
                                   int R, int C) {
  __shared__ float tile[32][33];
  const float* inb = in + (size_t)blockIdx.z * R * C;
  __hip_bfloat16* outb = out + (size_t)blockIdx.z * R * C;
  int cx = blockIdx.x * 32 + threadIdx.x;  // input col
  int ry = blockIdx.y * 32;                // input row base
  for (int j = threadIdx.y; j < 32; j += 8)
    tile[j][threadIdx.x] = inb[(size_t)(ry + j) * C + cx];
  __syncthreads();
  int ox = ry + threadIdx.x;  // output col = input row
  int oy = blockIdx.x * 32;   // output row base = input col base
  for (int j = threadIdx.y; j < 32; j += 8)
    outb[(size_t)(oy + j) * R + ox] = __float2bfloat16(tile[threadIdx.x][j]);
}

// ---------------------------------------------------------------------------
// MFMA GEMM (NT): C[M,N] = act(A[M,Kd] * Bt[N,Kd]^T + bias[N])
// 128x128 block tile, BK=32, 256 threads = 4 waves (2x2), each wave 4x4
// tiles of mfma_f32_16x16x32_bf16. global_load_lds width-16 staging.
// Batched over blockIdx.z with element strides sAz/sBz/sBiasZ/sCz.
// EPI: 1 = tanh->bf16, 2 = relu->bf16, 3 = plain->bf16
// ---------------------------------------------------------------------------
template <int EPI>
__global__ __launch_bounds__(256) void gemm_bt(
    const __hip_bfloat16* __restrict__ A, long sAz, int lda,
    const __hip_bfloat16* __restrict__ Bt, long sBz, int ldb,
    const float* __restrict__ bias, long sBiasZ,
    __hip_bfloat16* __restrict__ C, long sCz, int ldc, int Kd) {
  __shared__ __align__(16) __hip_bfloat16 As[128 * 32];
  __shared__ __align__(16) __hip_bfloat16 Bs[128 * 32];

  const int z = blockIdx.z;
  const __hip_bfloat16* Ab = A + (size_t)z * sAz;
  const __hip_bfloat16* Bb = Bt + (size_t)z * sBz;
  const float* biasb = bias + (size_t)z * sBiasZ;
  __hip_bfloat16* Cb = C + (size_t)z * sCz;

  const int bm = blockIdx.y, bn = blockIdx.x;
  const int t = threadIdx.x;
  const int lane = t & 63, w = t >> 6;
  const int wm = w >> 1, wn = w & 1;
  const int r = lane & 15, q = lane >> 4;

  f32x4 acc[4][4] = {};

  const int c0 = t, c1 = t + 256;
  const int rA0 = c0 >> 2, cc0 = (c0 & 3) * 8;
  const int rA1 = c1 >> 2, cc1 = (c1 & 3) * 8;
  const size_t rowA = (size_t)bm * 128, rowB = (size_t)bn * 128;

  for (int k0 = 0; k0 < Kd; k0 += 32) {
    __builtin_amdgcn_global_load_lds(
        (const __attribute__((address_space(1))) void*)(Ab + (rowA + rA0) * lda + k0 + cc0),
        (__attribute__((address_space(3))) void*)(As + c0 * 8), 16, 0, 0);
    __builtin_amdgcn_global_load_lds(
        (const __attribute__((address_space(1))) void*)(Ab + (rowA + rA1) * lda + k0 + cc1),
        (__attribute__((address_space(3))) void*)(As + c1 * 8), 16, 0, 0);
    __builtin_amdgcn_global_load_lds(
        (const __attribute__((address_space(1))) void*)(Bb + (rowB + rA0) * ldb + k0 + cc0),
        (__attribute__((address_space(3))) void*)(Bs + c0 * 8), 16, 0, 0);
    __builtin_amdgcn_global_load_lds(
        (const __attribute__((address_space(1))) void*)(Bb + (rowB + rA1) * ldb + k0 + cc1),
        (__attribute__((address_space(3))) void*)(Bs + c1 * 8), 16, 0, 0);
    __syncthreads();

    bf16x8 af[4], bfr[4];
#pragma unroll
    for (int mt = 0; mt < 4; ++mt)
      af[mt] = *(const bf16x8*)&As[(wm * 64 + mt * 16 + r) * 32 + q * 8];
#pragma unroll
    for (int nt = 0; nt < 4; ++nt)
      bfr[nt] = *(const bf16x8*)&Bs[(wn * 64 + nt * 16 + r) * 32 + q * 8];
#pragma unroll
    for (int mt = 0; mt < 4; ++mt)
#pragma unroll
      for (int nt = 0; nt < 4; ++nt)
        acc[mt][nt] = __builtin_amdgcn_mfma_f32_16x16x32_bf16(
            af[mt], bfr[nt], acc[mt][nt], 0, 0, 0);
    __syncthreads();
  }

  // Epilogue: C/D layout col = lane&15, row = q*4 + j  [m89-verified]
  const int colg0 = bn * 128 + wn * 64;
  const int rowg0 = bm * 128 + wm * 64;
#pragma unroll
  for (int nt = 0; nt < 4; ++nt) {
    int col = colg0 + nt * 16 + r;
    float bv = biasb[col];
#pragma unroll
    for (int mt = 0; mt < 4; ++mt) {
      int row0 = rowg0 + mt * 16 + q * 4;
#pragma unroll
      for (int j = 0; j < 4; ++j) {
        float v = acc[mt][nt][j] + bv;
        if (EPI == 1) v = tanhf(v);
        if (EPI == 2) v = fmaxf(v, 0.0f);
        Cb[(size_t)(row0 + j) * ldc + col] = __float2bfloat16(v);
      }
    }
  }
}

// ---------------------------------------------------------------------------
// Final: one WAVE per batch row b. Gram G = Z Z^T (Z: 12 x NH, padded to 16)
// via mfma(a, a, acc) — NT A/B fragment layouts are identical, so the same
// registers serve as both operands. Then 11 lanes compute the score terms.
// zc layout: [12, Bc, NH] bf16.
// ---------------------------------------------------------------------------
__global__ __launch_bounds__(256) void final_gram(
    const __hip_bfloat16* __restrict__ zc, float* __restrict__ out, int Bc) {
  __shared__ float Gs[4][16][16];
  const int t = threadIdx.x;
  const int w = t >> 6, lane = t & 63;
  const int b = blockIdx.x * 4 + w;
  const int r = lane & 15;   // slice index (row of A, col of B^T)
  const int q = lane >> 4;   // k-quad: covers k = q*8 .. q*8+7

  const int rs = r < 12 ? r : 11;
  const __hip_bfloat16* base = zc + ((size_t)rs * Bc + b) * NH + q * 8;

  f32x4 acc = {};
#pragma unroll
  for (int k0 = 0; k0 < NH; k0 += 32) {
    bf16x8 a = {};
    if (r < 12) a = *(const bf16x8*)(base + k0);
    acc = __builtin_amdgcn_mfma_f32_16x16x32_bf16(a, a, acc, 0, 0, 0);
  }

  // C/D layout: col = lane&15 = r, row = q*4 + j  -> Gs[row][col]
#pragma unroll
  for (int j = 0; j < 4; ++j) Gs[w][q * 4 + j][r] = acc[j];
  __syncthreads();

  // Score: lane l in 1..11 computes term for view k=l; sum via shfl in the
  // low 16-lane group; lane 0 writes.
  float term = 0.0f;
  if (lane >= 1 && lane < 12) {
    float nrm[12];
#pragma unroll
    for (int i = 0; i < 12; ++i)
      nrm[i] = fmaxf(sqrtf(Gs[w][i][i]), 1e-8f);
    const int k = lane;
    float pos = __expf(Gs[w][0][k] / (nrm[0] * nrm[k]));
    float neg = 0.0f;
#pragma unroll
    for (int l = 1; l < 12; ++l)
      if (l != k) neg += __expf(Gs[w][k][l] / (nrm[k] * nrm[l]));
    term = __logf(pos / (pos + neg));
  }
#pragma unroll
  for (int m = 1; m < 16; m <<= 1) term += __shfl_xor(term, m);
  if (lane == 0) out[b] = -term;
}

// ---------------------------------------------------------------------------
extern "C" void kernel_launch(void* const* d_in, const int* in_sizes, int n_in,
                              void* d_out, int out_size, void* d_ws,
                              size_t ws_size, hipStream_t stream) {
  const float* x = (const float*)d_in[0];    // [B,D]
  const float* Wt1 = (const float*)d_in[1];  // [K,D,H]
  const float* bt1 = (const float*)d_in[2];  // [K,H]
  const float* Wt2 = (const float*)d_in[3];  // [K,H,D]
  const float* bt2 = (const float*)d_in[4];  // [K,D]
  const float* We1 = (const float*)d_in[5];  // [D,H]
  const float* be1 = (const float*)d_in[6];  // [H]
  const float* We2 = (const float*)d_in[7];  // [H,H]
  const float* be2 = (const float*)d_in[8];  // [H]
  float* out = (float*)d_out;                // [B]

  char* ws = (char*)d_ws;
  size_t off = 0;
  auto alloc = [&](size_t bytes) {
    void* p = ws + off;
    off += (bytes + 255) & ~(size_t)255;
    return p;
  };

  // Persistent bf16 weight transposes (~26 MB)
  __hip_bfloat16* Wt1t = (__hip_bfloat16*)alloc((size_t)NK * NH * ND * 2);  // [K,H,D]
  __hip_bfloat16* Wt2t = (__hip_bfloat16*)alloc((size_t)NK * ND * NH * 2);  // [K,D,H]
  __hip_bfloat16* We1t = (__hip_bfloat16*)alloc((size_t)NH * ND * 2);       // [H,D]
  __hip_bfloat16* We2t = (__hip_bfloat16*)alloc((size_t)NH * NH * 2);       // [H,H]
  const size_t wbytes = off;

  // Pick largest batch chunk Bc whose buffers fit in ws_size.
  int Bc = NB;
  while (Bc > 128) {
    size_t need = wbytes + (size_t)12 * Bc * ND * 2 +
                  2 * ((size_t)12 * Bc * NH * 2) + 4096;
    if (need <= ws_size) break;
    Bc >>= 1;
  }
  // Per-chunk buffers:
  __hip_bfloat16* txc = (__hip_bfloat16*)alloc((size_t)12 * Bc * ND * 2);
  __hip_bfloat16* h1 = (__hip_bfloat16*)alloc((size_t)12 * Bc * NH * 2);
  __hip_bfloat16* zc = (__hip_bfloat16*)alloc((size_t)12 * Bc * NH * 2);

  // One-time weight transposes to bf16 [N][K] layout
  transpose_f32_bf16<<<dim3(NH / 32, ND / 32, NK), dim3(32, 8), 0, stream>>>(
      Wt1, Wt1t, ND, NH);
  transpose_f32_bf16<<<dim3(ND / 32, NH / 32, NK), dim3(32, 8), 0, stream>>>(
      Wt2, Wt2t, NH, ND);
  transpose_f32_bf16<<<dim3(NH / 32, ND / 32, 1), dim3(32, 8), 0, stream>>>(
      We1, We1t, ND, NH);
  transpose_f32_bf16<<<dim3(NH / 32, NH / 32, 1), dim3(32, 8), 0, stream>>>(
      We2, We2t, NH, NH);

  for (int cs = 0; cs < NB; cs += Bc) {
    // 1) x chunk -> bf16 (slice 0 of txc)
    cvt_f32_bf16<<<(Bc * ND) / 256, 256, 0, stream>>>(
        x + (size_t)cs * ND, txc, Bc * ND);
    // 2) G1: hx_k = tanh(x @ Wt1[k] + bt1) -> h1 slices 0..10  (M=Bc,N=H,Kd=D)
    gemm_bt<1><<<dim3(NH / 128, Bc / 128, NK), 256, 0, stream>>>(
        txc, 0L, ND, Wt1t, (long)NH * ND, ND, bt1, (long)NH, h1,
        (long)Bc * NH, NH, ND);
    // 3) G2: tx_k = hx_k @ Wt2[k] + bt2 -> txc slices 1..11    (M=Bc,N=D,Kd=H)
    gemm_bt<3><<<dim3(ND / 128, Bc / 128, NK), 256, 0, stream>>>(
        h1, (long)Bc * NH, NH, Wt2t, (long)ND * NH, NH, bt2, (long)ND,
        txc + (size_t)Bc * ND, (long)Bc * ND, ND, NH);
    // 4) G3: e1_s = relu(tx_s @ We1 + be1) -> h1 slices 0..11  (M=Bc,N=H,Kd=D)
    gemm_bt<2><<<dim3(NH / 128, Bc / 128, 12), 256, 0, stream>>>(
        txc, (long)Bc * ND, ND, We1t, 0L, ND, be1, 0L, h1, (long)Bc * NH,
        NH, ND);
    // 5) G4: z_s = e1_s @ We2 + be2 -> zc slices 0..11         (M=Bc,N=H,Kd=H)
    gemm_bt<3><<<dim3(NH / 128, Bc / 128, 12), 256, 0, stream>>>(
        h1, (long)Bc * NH, NH, We2t, 0L, NH, be2, 0L, zc, (long)Bc * NH,
        NH, NH);
    // 6) final score for this chunk: one wave per batch row
    final_gram<<<Bc / 4, 256, 0, stream>>>(zc, out + cs, Bc);
  }
}

// Round 4
// 951.031 us; speedup vs baseline: 1.6626x; 1.1220x over previous
//
#include <hip/hip_runtime.h>
#include <hip/hip_bf16.h>
#include <cstdint>
#include <cstddef>

// Problem constants (NeuTraLAD): B=8192, D=512, H=1024, K=11 views.
#define NB 8192
#define ND 512
#define NH 1024
#define NK 11

typedef __bf16 bf16x8 __attribute__((ext_vector_type(8)));
typedef float f32x4 __attribute__((ext_vector_type(4)));

// ---------------------------------------------------------------------------
// Convert f32 -> bf16 elementwise
// ---------------------------------------------------------------------------
__global__ void cvt_f32_bf16(const float* __restrict__ in,
                             __hip_bfloat16* __restrict__ out, int n) {
  int i = blockIdx.x * blockDim.x + threadIdx.x;
  if (i < n) out[i] = __float2bfloat16(in[i]);
}

// ---------------------------------------------------------------------------
// Transpose f32 [R,C] -> bf16 [C,R], batched over blockIdx.z (stride R*C)
// ---------------------------------------------------------------------------
__global__ void transpose_f32_bf16(const float* __restrict__ in,
                                   __hip_bfloat16* __restrict__ out,
                                   int R, int C) {
  __shared__ float tile[32][33];
  const float* inb = in + (size_t)blockIdx.z * R * C;
  __hip_bfloat16* outb = out + (size_t)blockIdx.z * R * C;
  int cx = blockIdx.x * 32 + threadIdx.x;  // input col
  int ry = blockIdx.y * 32;                // input row base
  for (int j = threadIdx.y; j < 32; j += 8)
    tile[j][threadIdx.x] = inb[(size_t)(ry + j) * C + cx];
  __syncthreads();
  int ox = ry + threadIdx.x;  // output col = input row
  int oy = blockIdx.x * 32;   // output row base = input col base
  for (int j = threadIdx.y; j < 32; j += 8)
    outb[(size_t)(oy + j) * R + ox] = __float2bfloat16(tile[threadIdx.x][j]);
}

__device__ __forceinline__ float fast_tanh(float x) {
  // tanh(x) = 1 - 2/(exp(2x)+1); __expf-based, bf16-accurate.
  float e = __expf(2.0f * x);
  return 1.0f - 2.0f / (e + 1.0f);
}

// ---------------------------------------------------------------------------
// MFMA GEMM (NT): C[M,N] = act(A[M,Kd] * Bt[N,Kd]^T + bias[N])
// 128x128 block tile, BK=32, 256 threads = 4 waves (2x2), each wave 4x4
// tiles of mfma_f32_16x16x32_bf16. global_load_lds width-16 staging.
// GRID: x = row panel (M/128), y = col panel (N/128) — so the 8 col-blocks
// of one row panel share id mod 8 -> same XCD -> A panel stays L2-hot.
// LDS chunk slots XOR-swizzled: chunk q of row stored at slot q^((row>>1)&3)
// -> conflict-free ds_read_b128 phases, staging coalescing preserved.
// EPI: 1 = tanh->bf16, 2 = relu->bf16, 3 = plain->bf16
// ---------------------------------------------------------------------------
template <int EPI>
__global__ __launch_bounds__(256) void gemm_bt(
    const __hip_bfloat16* __restrict__ A, long sAz, int lda,
    const __hip_bfloat16* __restrict__ Bt, long sBz, int ldb,
    const float* __restrict__ bias, long sBiasZ,
    __hip_bfloat16* __restrict__ C, long sCz, int ldc, int Kd) {
  __shared__ __align__(16) __hip_bfloat16 As[128 * 32];
  __shared__ __align__(16) __hip_bfloat16 Bs[128 * 32];

  const int z = blockIdx.z;
  const __hip_bfloat16* Ab = A + (size_t)z * sAz;
  const __hip_bfloat16* Bb = Bt + (size_t)z * sBz;
  const float* biasb = bias + (size_t)z * sBiasZ;
  __hip_bfloat16* Cb = C + (size_t)z * sCz;

  const int bm = blockIdx.x, bn = blockIdx.y;  // x = row panel (XCD affinity)
  const int t = threadIdx.x;
  const int lane = t & 63, w = t >> 6;
  const int wm = w >> 1, wn = w & 1;
  const int r = lane & 15, q = lane >> 4;

  f32x4 acc[4][4] = {};

  // staging chunks: c in [0,512), row = c>>2, slot-chunk cc = c&3.
  // slot (row, cc) holds global chunk cc ^ ((row>>1)&3).
  const int c0 = t, c1 = t + 256;
  const int rA0 = c0 >> 2, rA1 = c1 >> 2;
  const int sw0 = ((c0 & 3) ^ ((rA0 >> 1) & 3)) * 8;
  const int sw1 = ((c1 & 3) ^ ((rA1 >> 1) & 3)) * 8;
  const size_t rowA = (size_t)bm * 128, rowB = (size_t)bn * 128;

  for (int k0 = 0; k0 < Kd; k0 += 32) {
    __builtin_amdgcn_global_load_lds(
        (const __attribute__((address_space(1))) void*)(Ab + (rowA + rA0) * lda + k0 + sw0),
        (__attribute__((address_space(3))) void*)(As + c0 * 8), 16, 0, 0);
    __builtin_amdgcn_global_load_lds(
        (const __attribute__((address_space(1))) void*)(Ab + (rowA + rA1) * lda + k0 + sw1),
        (__attribute__((address_space(3))) void*)(As + c1 * 8), 16, 0, 0);
    __builtin_amdgcn_global_load_lds(
        (const __attribute__((address_space(1))) void*)(Bb + (rowB + rA0) * ldb + k0 + sw0),
        (__attribute__((address_space(3))) void*)(Bs + c0 * 8), 16, 0, 0);
    __builtin_amdgcn_global_load_lds(
        (const __attribute__((address_space(1))) void*)(Bb + (rowB + rA1) * ldb + k0 + sw1),
        (__attribute__((address_space(3))) void*)(Bs + c1 * 8), 16, 0, 0);
    __syncthreads();

    bf16x8 af[4], bfr[4];
#pragma unroll
    for (int mt = 0; mt < 4; ++mt) {
      int row = wm * 64 + mt * 16 + r;
      af[mt] = *(const bf16x8*)&As[row * 32 + (q ^ ((row >> 1) & 3)) * 8];
    }
#pragma unroll
    for (int nt = 0; nt < 4; ++nt) {
      int row = wn * 64 + nt * 16 + r;
      bfr[nt] = *(const bf16x8*)&Bs[row * 32 + (q ^ ((row >> 1) & 3)) * 8];
    }
#pragma unroll
    for (int mt = 0; mt < 4; ++mt)
#pragma unroll
      for (int nt = 0; nt < 4; ++nt)
        acc[mt][nt] = __builtin_amdgcn_mfma_f32_16x16x32_bf16(
            af[mt], bfr[nt], acc[mt][nt], 0, 0, 0);
    __syncthreads();
  }

  // Epilogue: C/D layout col = lane&15, row = q*4 + j  [m89-verified]
  const int colg0 = bn * 128 + wn * 64;
  const int rowg0 = bm * 128 + wm * 64;
#pragma unroll
  for (int nt = 0; nt < 4; ++nt) {
    int col = colg0 + nt * 16 + r;
    float bv = biasb[col];
#pragma unroll
    for (int mt = 0; mt < 4; ++mt) {
      int row0 = rowg0 + mt * 16 + q * 4;
#pragma unroll
      for (int j = 0; j < 4; ++j) {
        float v = acc[mt][nt][j] + bv;
        if (EPI == 1) v = fast_tanh(v);
        if (EPI == 2) v = fmaxf(v, 0.0f);
        Cb[(size_t)(row0 + j) * ldc + col] = __float2bfloat16(v);
      }
    }
  }
}

// ---------------------------------------------------------------------------
// Final: one WAVE per batch row b. Gram G = Z Z^T (Z: 12 x NH, padded to 16)
// via mfma(a, a, acc) — NT A/B fragment layouts are identical.
// zc layout: [12, Bc, NH] bf16.
// ---------------------------------------------------------------------------
__global__ __launch_bounds__(256) void final_gram(
    const __hip_bfloat16* __restrict__ zc, float* __restrict__ out, int Bc) {
  __shared__ float Gs[4][16][16];
  const int t = threadIdx.x;
  const int w = t >> 6, lane = t & 63;
  const int b = blockIdx.x * 4 + w;
  const int r = lane & 15;   // slice index
  const int q = lane >> 4;   // k-quad

  const int rs = r < 12 ? r : 11;
  const __hip_bfloat16* base = zc + ((size_t)rs * Bc + b) * NH + q * 8;

  f32x4 acc = {};
#pragma unroll
  for (int k0 = 0; k0 < NH; k0 += 32) {
    bf16x8 a = {};
    if (r < 12) a = *(const bf16x8*)(base + k0);
    acc = __builtin_amdgcn_mfma_f32_16x16x32_bf16(a, a, acc, 0, 0, 0);
  }

#pragma unroll
  for (int j = 0; j < 4; ++j) Gs[w][q * 4 + j][r] = acc[j];
  __syncthreads();

  float term = 0.0f;
  if (lane >= 1 && lane < 12) {
    float nrm[12];
#pragma unroll
    for (int i = 0; i < 12; ++i)
      nrm[i] = fmaxf(sqrtf(Gs[w][i][i]), 1e-8f);
    const int k = lane;
    float pos = __expf(Gs[w][0][k] / (nrm[0] * nrm[k]));
    float neg = 0.0f;
#pragma unroll
    for (int l = 1; l < 12; ++l)
      if (l != k) neg += __expf(Gs[w][k][l] / (nrm[k] * nrm[l]));
    term = __logf(pos / (pos + neg));
  }
#pragma unroll
  for (int m = 1; m < 16; m <<= 1) term += __shfl_xor(term, m);
  if (lane == 0) out[b] = -term;
}

// ---------------------------------------------------------------------------
extern "C" void kernel_launch(void* const* d_in, const int* in_sizes, int n_in,
                              void* d_out, int out_size, void* d_ws,
                              size_t ws_size, hipStream_t stream) {
  const float* x = (const float*)d_in[0];    // [B,D]
  const float* Wt1 = (const float*)d_in[1];  // [K,D,H]
  const float* bt1 = (const float*)d_in[2];  // [K,H]
  const float* Wt2 = (const float*)d_in[3];  // [K,H,D]
  const float* bt2 = (const float*)d_in[4];  // [K,D]
  const float* We1 = (const float*)d_in[5];  // [D,H]
  const float* be1 = (const float*)d_in[6];  // [H]
  const float* We2 = (const float*)d_in[7];  // [H,H]
  const float* be2 = (const float*)d_in[8];  // [H]
  float* out = (float*)d_out;                // [B]

  char* ws = (char*)d_ws;
  size_t off = 0;
  auto alloc = [&](size_t bytes) {
    void* p = ws + off;
    off += (bytes + 255) & ~(size_t)255;
    return p;
  };

  // Persistent bf16 weight transposes (~26 MB)
  __hip_bfloat16* Wt1t = (__hip_bfloat16*)alloc((size_t)NK * NH * ND * 2);  // [K,H,D]
  __hip_bfloat16* Wt2t = (__hip_bfloat16*)alloc((size_t)NK * ND * NH * 2);  // [K,D,H]
  __hip_bfloat16* We1t = (__hip_bfloat16*)alloc((size_t)NH * ND * 2);       // [H,D]
  __hip_bfloat16* We2t = (__hip_bfloat16*)alloc((size_t)NH * NH * 2);       // [H,H]
  const size_t wbytes = off;

  // Pick largest batch chunk Bc whose buffers fit in ws_size.
  int Bc = NB;
  while (Bc > 128) {
    size_t need = wbytes + (size_t)12 * Bc * ND * 2 +
                  2 * ((size_t)12 * Bc * NH * 2) + 4096;
    if (need <= ws_size) break;
    Bc >>= 1;
  }
  // Per-chunk buffers:
  __hip_bfloat16* txc = (__hip_bfloat16*)alloc((size_t)12 * Bc * ND * 2);
  __hip_bfloat16* h1 = (__hip_bfloat16*)alloc((size_t)12 * Bc * NH * 2);
  __hip_bfloat16* zc = (__hip_bfloat16*)alloc((size_t)12 * Bc * NH * 2);

  // One-time weight transposes to bf16 [N][K] layout
  transpose_f32_bf16<<<dim3(NH / 32, ND / 32, NK), dim3(32, 8), 0, stream>>>(
      Wt1, Wt1t, ND, NH);
  transpose_f32_bf16<<<dim3(ND / 32, NH / 32, NK), dim3(32, 8), 0, stream>>>(
      Wt2, Wt2t, NH, ND);
  transpose_f32_bf16<<<dim3(NH / 32, ND / 32, 1), dim3(32, 8), 0, stream>>>(
      We1, We1t, ND, NH);
  transpose_f32_bf16<<<dim3(NH / 32, NH / 32, 1), dim3(32, 8), 0, stream>>>(
      We2, We2t, NH, NH);

  for (int cs = 0; cs < NB; cs += Bc) {
    // 1) x chunk -> bf16 (slice 0 of txc)
    cvt_f32_bf16<<<(Bc * ND) / 256, 256, 0, stream>>>(
        x + (size_t)cs * ND, txc, Bc * ND);
    // 2) G1: hx_k = tanh(x @ Wt1[k] + bt1) -> h1 slices 0..10  (M=Bc,N=H,Kd=D)
    gemm_bt<1><<<dim3(Bc / 128, NH / 128, NK), 256, 0, stream>>>(
        txc, 0L, ND, Wt1t, (long)NH * ND, ND, bt1, (long)NH, h1,
        (long)Bc * NH, NH, ND);
    // 3) G2: tx_k = hx_k @ Wt2[k] + bt2 -> txc slices 1..11    (M=Bc,N=D,Kd=H)
    gemm_bt<3><<<dim3(Bc / 128, ND / 128, NK), 256, 0, stream>>>(
        h1, (long)Bc * NH, NH, Wt2t, (long)ND * NH, NH, bt2, (long)ND,
        txc + (size_t)Bc * ND, (long)Bc * ND, ND, NH);
    // 4) G3: e1_s = relu(tx_s @ We1 + be1) -> h1 slices 0..11  (M=Bc,N=H,Kd=D)
    gemm_bt<2><<<dim3(Bc / 128, NH / 128, 12), 256, 0, stream>>>(
        txc, (long)Bc * ND, ND, We1t, 0L, ND, be1, 0L, h1, (long)Bc * NH,
        NH, ND);
    // 5) G4: z_s = e1_s @ We2 + be2 -> zc slices 0..11         (M=Bc,N=H,Kd=H)
    gemm_bt<3><<<dim3(Bc / 128, NH / 128, 12), 256, 0, stream>>>(
        h1, (long)Bc * NH, NH, We2t, 0L, NH, be2, 0L, zc, (long)Bc * NH,
        NH, NH);
    // 6) final score for this chunk: one wave per batch row
    final_gram<<<Bc / 4, 256, 0, stream>>>(zc, out + cs, Bc);
  }
}